// Round 7
// baseline (33030.496 us; speedup 1.0000x reference)
//
#include <hip/hip_runtime.h>
#include <stdint.h>

#define B_ 64
#define T_ 2048
#define I_ 256
#define H_ 256
#define G3 768

typedef _Float16 half8v __attribute__((ext_vector_type(8)));
typedef float f32x4 __attribute__((ext_vector_type(4)));

#define MFMA16(a, b, c) __builtin_amdgcn_mfma_f32_16x16x32_f16((a), (b), (c), 0, 0, 0)

// ---------------- Phase 1: gi GEMM (round-0 verbatim, proven ~760us) ----------------
__global__ __launch_bounds__(256) void gi_gemm(
    const float* __restrict__ x, const float* __restrict__ Wih,
    const float* __restrict__ bih, const float* __restrict__ bhh,
    float* __restrict__ gi, int t0)
{
  const int t  = t0 + blockIdx.x;
  const int n0 = blockIdx.y * 64;
  __shared__ float As[32][68];
  __shared__ float Bs[32][68];
  const int tid = threadIdx.x;
  const int ty = tid >> 4, tx = tid & 15;
  const int lr = tid >> 3;
  const int lk = (tid & 7) << 2;
  float acc[4][4] = {};

  for (int kc = 0; kc < I_; kc += 32) {
    float4 a0 = *(const float4*)(x + ((size_t)lr        * T_ + t) * I_ + kc + lk);
    float4 a1 = *(const float4*)(x + ((size_t)(lr + 32) * T_ + t) * I_ + kc + lk);
    float4 b0 = *(const float4*)(Wih + (size_t)(n0 + lr)      * I_ + kc + lk);
    float4 b1 = *(const float4*)(Wih + (size_t)(n0 + lr + 32) * I_ + kc + lk);
    __syncthreads();
    As[lk+0][lr]    = a0.x; As[lk+1][lr]    = a0.y; As[lk+2][lr]    = a0.z; As[lk+3][lr]    = a0.w;
    As[lk+0][lr+32] = a1.x; As[lk+1][lr+32] = a1.y; As[lk+2][lr+32] = a1.z; As[lk+3][lr+32] = a1.w;
    Bs[lk+0][lr]    = b0.x; Bs[lk+1][lr]    = b0.y; Bs[lk+2][lr]    = b0.z; Bs[lk+3][lr]    = b0.w;
    Bs[lk+0][lr+32] = b1.x; Bs[lk+1][lr+32] = b1.y; Bs[lk+2][lr+32] = b1.z; Bs[lk+3][lr+32] = b1.w;
    __syncthreads();
    #pragma unroll
    for (int kk = 0; kk < 32; ++kk) {
      float4 av = *(const float4*)(&As[kk][ty << 2]);
      float4 bv = *(const float4*)(&Bs[kk][tx << 2]);
      float av_[4] = {av.x, av.y, av.z, av.w};
      float bv_[4] = {bv.x, bv.y, bv.z, bv.w};
      #pragma unroll
      for (int i = 0; i < 4; ++i)
        #pragma unroll
        for (int u = 0; u < 4; ++u)
          acc[i][u] = fmaf(av_[i], bv_[u], acc[i][u]);
    }
  }

  const int colb = n0 + (tx << 2);
  float4 bi = *(const float4*)(bih + colb);
  float4 bh = *(const float4*)(bhh + colb);
  float4 badd;
  badd.x = bi.x + (colb + 0 < 512 ? bh.x : 0.f);
  badd.y = bi.y + (colb + 1 < 512 ? bh.y : 0.f);
  badd.z = bi.z + (colb + 2 < 512 ? bh.z : 0.f);
  badd.w = bi.w + (colb + 3 < 512 ? bh.w : 0.f);
  float* gout = gi + (size_t)blockIdx.x * 64 * G3;
  #pragma unroll
  for (int i = 0; i < 4; ++i) {
    int bb = (ty << 2) + i;
    float4 o;
    o.x = acc[i][0] + badd.x; o.y = acc[i][1] + badd.y;
    o.z = acc[i][2] + badd.z; o.w = acc[i][3] + badd.w;
    *(float4*)(gout + (size_t)bb * G3 + colb) = o;
  }
}

// ---------------- Phase 2: MFMA recurrence ----------------
// 4 blocks x 16 batches, 256 threads = 4 waves (1 wave/SIMD, up to 512 VGPR).
// Wave w owns hidden cols [w*64, w*64+64): 12 tiles (r,z,n x 4 hidden-16) of 16x16x32.
// W_hh fragments live in registers (96 x half8 = 384 VGPR, loaded once).
// h: f32 in owning lanes (C layout: col=lane&15, row=(lane>>4)*4+i) + f16 copy in
// double-buffered LDS [16][264] (row stride 528B; j-offset XOR'd with (row&8)<<2 for
// conflict-free writes) for the per-step A-fragment rebuild (8 x ds_read_b128).
// A/B frag layout: idx=lane&15, k=(lane>>4)*8+e -- any consistent k-permutation cancels
// between A and B. One __syncthreads per step; all loads consumed within the step.
__global__ __launch_bounds__(256, 1) void gru_mfma(
    const float* __restrict__ gi, const float* __restrict__ att,
    const int* __restrict__ lengths, const float* __restrict__ Whh,
    const float* __restrict__ bhh, float* __restrict__ hws,
    float* __restrict__ out, int t0, int t1)
{
  __shared__ __align__(16) _Float16 hlds[2][16][264];   // 2 x 8448 B
  const int tid  = threadIdx.x;
  const int w    = tid >> 6;
  const int lane = tid & 63;
  const int c    = lane & 15;        // A row / B-C col
  const int g4   = lane >> 4;        // k-group / C row-group
  const int bset = blockIdx.x * 16;
  const int b0   = bset + 4 * g4;    // lane's first batch (C rows 4*g4..+3)

  // ---- W_hh fragments (prologue only) ----
  half8v wf[3][4][8];                // [gate][hidden-tile][kfrag]
  #pragma unroll
  for (int g = 0; g < 3; ++g)
    #pragma unroll
    for (int ht = 0; ht < 4; ++ht)
      #pragma unroll
      for (int kf = 0; kf < 8; ++kf) {
        const float* src = Whh + (size_t)(g * 256 + w * 64 + ht * 16 + c) * H_
                               + kf * 32 + g4 * 8;
        float4 u0 = *(const float4*)(src);
        float4 u1 = *(const float4*)(src + 4);
        half8v v;
        v[0] = (_Float16)u0.x; v[1] = (_Float16)u0.y;
        v[2] = (_Float16)u0.z; v[3] = (_Float16)u0.w;
        v[4] = (_Float16)u1.x; v[5] = (_Float16)u1.y;
        v[6] = (_Float16)u1.z; v[7] = (_Float16)u1.w;
        wf[g][ht][kf] = v;
      }

  float bhn[4];
  #pragma unroll
  for (int ht = 0; ht < 4; ++ht) bhn[ht] = bhh[512 + w * 64 + ht * 16 + c];
  int len4[4];
  #pragma unroll
  for (int i = 0; i < 4; ++i) len4[i] = lengths[b0 + i];
  const float* attb[4];
  #pragma unroll
  for (int i = 0; i < 4; ++i) attb[i] = att + (size_t)(b0 + i) * T_;

  // h carry + LDS buffer 0 init
  float h[4][4];                     // [hidden-tile][batch-sub]
  #pragma unroll
  for (int ht = 0; ht < 4; ++ht)
    #pragma unroll
    for (int i = 0; i < 4; ++i) {
      float v = (t0 > 0) ? hws[(size_t)(b0 + i) * H_ + w * 64 + ht * 16 + c] : 0.f;
      h[ht][i] = v;
      int row = 4 * g4 + i;
      *(_Float16*)((char*)hlds + row * 528 +
                   (((w * 64 + ht * 16 + c) * 2) ^ ((row & 8) << 2))) = (_Float16)v;
    }
  __syncthreads();

  const f32x4 zero4 = {0.f, 0.f, 0.f, 0.f};
  int p = 0;
  for (int t = t0; t < t1; ++t) {
    // ---- A fragments from LDS (8 x ds_read_b128, XOR-swizzled, conflict-free) ----
    const char* hbase = (const char*)hlds + p * 8448 + c * 528;
    const int xr = (c & 8) << 2;
    half8v a[8];
    #pragma unroll
    for (int kf = 0; kf < 8; ++kf)
      a[kf] = *(const half8v*)(hbase + ((kf * 64 + g4 * 16) ^ xr));

    // ---- gi/att loads, issued early (consumed in epilogues ~400cy later) ----
    const float* gb0 = gi + ((size_t)(t - t0) * B_ + b0) * G3 + w * 64 + c;
    float gi1[3][2][4], gi2[3][2][4], wat[4];
    #pragma unroll
    for (int i = 0; i < 4; ++i) {
      const float* gp = gb0 + (size_t)i * G3;
      #pragma unroll
      for (int g = 0; g < 3; ++g) {
        gi1[g][0][i] = gp[g * 256 +  0]; gi1[g][1][i] = gp[g * 256 + 16];
        gi2[g][0][i] = gp[g * 256 + 32]; gi2[g][1][i] = gp[g * 256 + 48];
      }
      wat[i] = attb[i][t];
    }

    char* wnext = (char*)hlds + (p ^ 1) * 8448;

    // ================= pass 1: hidden-tiles 0,1 =================
    f32x4 acc[3][2];
    #pragma unroll
    for (int g = 0; g < 3; ++g)
      #pragma unroll
      for (int h2 = 0; h2 < 2; ++h2)
        acc[g][h2] = MFMA16(a[0], wf[g][h2][0], zero4);
    #pragma unroll
    for (int kf = 1; kf < 8; ++kf)
      #pragma unroll
      for (int g = 0; g < 3; ++g)
        #pragma unroll
        for (int h2 = 0; h2 < 2; ++h2)
          acc[g][h2] = MFMA16(a[kf], wf[g][h2][kf], acc[g][h2]);

    #pragma unroll
    for (int h2 = 0; h2 < 2; ++h2) {
      const int ht = h2;
      #pragma unroll
      for (int i = 0; i < 4; ++i) {
        float gr = gi1[0][h2][i] + acc[0][h2][i];
        float gz = gi1[1][h2][i] + acc[1][h2][i];
        float r  = 1.f / (1.f + __expf(-gr));
        float z  = 1.f / (1.f + __expf(-gz));
        float e2 = __expf(2.f * (gi1[2][h2][i] + r * (acc[2][h2][i] + bhn[ht])));
        float nn = 1.f - 2.f / (e2 + 1.f);
        float hold = h[ht][i];
        float hnew = (1.f - z) * nn + z * hold;
        float hg   = wat[i] * hnew + (1.f - wat[i]) * hold;
        float hv   = (t < len4[i]) ? hg : hold;
        h[ht][i] = hv;
        int row = 4 * g4 + i;
        *(_Float16*)(wnext + row * 528 +
                     (((w * 64 + ht * 16 + c) * 2) ^ ((row & 8) << 2))) = (_Float16)hv;
      }
    }

    // ================= pass 2: hidden-tiles 2,3 =================
    #pragma unroll
    for (int g = 0; g < 3; ++g)
      #pragma unroll
      for (int h2 = 0; h2 < 2; ++h2)
        acc[g][h2] = MFMA16(a[0], wf[g][2 + h2][0], zero4);
    #pragma unroll
    for (int kf = 1; kf < 8; ++kf)
      #pragma unroll
      for (int g = 0; g < 3; ++g)
        #pragma unroll
        for (int h2 = 0; h2 < 2; ++h2)
          acc[g][h2] = MFMA16(a[kf], wf[g][2 + h2][kf], acc[g][h2]);

    #pragma unroll
    for (int h2 = 0; h2 < 2; ++h2) {
      const int ht = 2 + h2;
      #pragma unroll
      for (int i = 0; i < 4; ++i) {
        float gr = gi2[0][h2][i] + acc[0][h2][i];
        float gz = gi2[1][h2][i] + acc[1][h2][i];
        float r  = 1.f / (1.f + __expf(-gr));
        float z  = 1.f / (1.f + __expf(-gz));
        float e2 = __expf(2.f * (gi2[2][h2][i] + r * (acc[2][h2][i] + bhn[ht])));
        float nn = 1.f - 2.f / (e2 + 1.f);
        float hold = h[ht][i];
        float hnew = (1.f - z) * nn + z * hold;
        float hg   = wat[i] * hnew + (1.f - wat[i]) * hold;
        float hv   = (t < len4[i]) ? hg : hold;
        h[ht][i] = hv;
        int row = 4 * g4 + i;
        *(_Float16*)(wnext + row * 528 +
                     (((w * 64 + ht * 16 + c) * 2) ^ ((row & 8) << 2))) = (_Float16)hv;
      }
    }

    __syncthreads();   // nothing in flight: all loads consumed this step
    p ^= 1;
  }

  #pragma unroll
  for (int ht = 0; ht < 4; ++ht)
    #pragma unroll
    for (int i = 0; i < 4; ++i) {
      size_t idx = (size_t)(b0 + i) * H_ + w * 64 + ht * 16 + c;
      hws[idx] = h[ht][i];
      if (t1 == T_) out[idx] = h[ht][i];
    }
}

extern "C" void kernel_launch(void* const* d_in, const int* in_sizes, int n_in,
                              void* d_out, int out_size, void* d_ws, size_t ws_size,
                              hipStream_t stream)
{
  const float* x       = (const float*)d_in[0];
  const float* att     = (const float*)d_in[1];
  const int*   lengths = (const int*)d_in[2];
  const float* Wih     = (const float*)d_in[3];
  const float* Whh     = (const float*)d_in[4];
  const float* bih     = (const float*)d_in[5];
  const float* bhh     = (const float*)d_in[6];
  float* out = (float*)d_out;

  float* hws = (float*)d_ws;                         // 64 KiB
  float* gi  = (float*)((char*)d_ws + 65536);
  const size_t used0 = 65536;
  const size_t per_t = (size_t)B_ * G3 * sizeof(float);
  size_t avail = ws_size > used0 ? ws_size - used0 : 0;
  int Tc = (int)(avail / per_t);
  if (Tc > T_) Tc = T_;
  if (Tc < 1) Tc = 1;

  for (int t0 = 0; t0 < T_; t0 += Tc) {
    int t1 = t0 + Tc; if (t1 > T_) t1 = T_;
    dim3 g1(t1 - t0, G3 / 64);
    gi_gemm<<<g1, 256, 0, stream>>>(x, Wih, bih, bhh, gi, t0);
    gru_mfma<<<4, 256, 0, stream>>>(gi, att, lengths, Whh, bhh, hws, out, t0, t1);
  }
}

// Round 8
// 11406.257 us; speedup vs baseline: 2.8958x; 2.8958x over previous
//
#include <hip/hip_runtime.h>
#include <stdint.h>

#define B_ 64
#define T_ 2048
#define I_ 256
#define H_ 256
#define G3 768

typedef _Float16 half8v __attribute__((ext_vector_type(8)));
typedef float f32x4 __attribute__((ext_vector_type(4)));

#define MFMA16(a, b, c) __builtin_amdgcn_mfma_f32_16x16x32_f16((a), (b), (c), 0, 0, 0)

// ---------------- Phase 1: gi GEMM (round-0 verbatim, proven ~760us) ----------------
__global__ __launch_bounds__(256) void gi_gemm(
    const float* __restrict__ x, const float* __restrict__ Wih,
    const float* __restrict__ bih, const float* __restrict__ bhh,
    float* __restrict__ gi, int t0)
{
  const int t  = t0 + blockIdx.x;
  const int n0 = blockIdx.y * 64;
  __shared__ float As[32][68];
  __shared__ float Bs[32][68];
  const int tid = threadIdx.x;
  const int ty = tid >> 4, tx = tid & 15;
  const int lr = tid >> 3;
  const int lk = (tid & 7) << 2;
  float acc[4][4] = {};

  for (int kc = 0; kc < I_; kc += 32) {
    float4 a0 = *(const float4*)(x + ((size_t)lr        * T_ + t) * I_ + kc + lk);
    float4 a1 = *(const float4*)(x + ((size_t)(lr + 32) * T_ + t) * I_ + kc + lk);
    float4 b0 = *(const float4*)(Wih + (size_t)(n0 + lr)      * I_ + kc + lk);
    float4 b1 = *(const float4*)(Wih + (size_t)(n0 + lr + 32) * I_ + kc + lk);
    __syncthreads();
    As[lk+0][lr]    = a0.x; As[lk+1][lr]    = a0.y; As[lk+2][lr]    = a0.z; As[lk+3][lr]    = a0.w;
    As[lk+0][lr+32] = a1.x; As[lk+1][lr+32] = a1.y; As[lk+2][lr+32] = a1.z; As[lk+3][lr+32] = a1.w;
    Bs[lk+0][lr]    = b0.x; Bs[lk+1][lr]    = b0.y; Bs[lk+2][lr]    = b0.z; Bs[lk+3][lr]    = b0.w;
    Bs[lk+0][lr+32] = b1.x; Bs[lk+1][lr+32] = b1.y; Bs[lk+2][lr+32] = b1.z; Bs[lk+3][lr+32] = b1.w;
    __syncthreads();
    #pragma unroll
    for (int kk = 0; kk < 32; ++kk) {
      float4 av = *(const float4*)(&As[kk][ty << 2]);
      float4 bv = *(const float4*)(&Bs[kk][tx << 2]);
      float av_[4] = {av.x, av.y, av.z, av.w};
      float bv_[4] = {bv.x, bv.y, bv.z, bv.w};
      #pragma unroll
      for (int i = 0; i < 4; ++i)
        #pragma unroll
        for (int u = 0; u < 4; ++u)
          acc[i][u] = fmaf(av_[i], bv_[u], acc[i][u]);
    }
  }

  const int colb = n0 + (tx << 2);
  float4 bi = *(const float4*)(bih + colb);
  float4 bh = *(const float4*)(bhh + colb);
  float4 badd;
  badd.x = bi.x + (colb + 0 < 512 ? bh.x : 0.f);
  badd.y = bi.y + (colb + 1 < 512 ? bh.y : 0.f);
  badd.z = bi.z + (colb + 2 < 512 ? bh.z : 0.f);
  badd.w = bi.w + (colb + 3 < 512 ? bh.w : 0.f);
  float* gout = gi + (size_t)blockIdx.x * 64 * G3;
  #pragma unroll
  for (int i = 0; i < 4; ++i) {
    int bb = (ty << 2) + i;
    float4 o;
    o.x = acc[i][0] + badd.x; o.y = acc[i][1] + badd.y;
    o.z = acc[i][2] + badd.z; o.w = acc[i][3] + badd.w;
    *(float4*)(gout + (size_t)bb * G3 + colb) = o;
  }
}

// ---------------- Phase 2: MFMA recurrence (round-7 math, AGPR-pinned weights) ----------------
// Round-7 lesson: wf[3][4][8] = 384 VGPR/lane; compiler capped arch VGPRs at 256 and
// spilled ~130 regs to MEMORY scratch -> 38000 cy/step, all pipes idle. gfx950 MFMA
// reads A/B from VGPR or AGPR (unified 512-reg file at 1 wave/SIMD: 256 arch + 256 acc).
// Fix: pin gates r,z (64 frags = 256 AGPRs, the AGPR cap) via empty asm "+a"; gate n
// (128 VGPR) stays arch. gi loads split per-pass (24 live, not 48). len folded into wat.
__global__ __launch_bounds__(256, 1) void gru_mfma(
    const float* __restrict__ gi, const float* __restrict__ att,
    const int* __restrict__ lengths, const float* __restrict__ Whh,
    const float* __restrict__ bhh, float* __restrict__ hws,
    float* __restrict__ out, int t0, int t1)
{
  __shared__ __align__(16) _Float16 hlds[2][16][264];   // 2 x 8448 B
  const int tid  = threadIdx.x;
  const int w    = tid >> 6;
  const int lane = tid & 63;
  const int c    = lane & 15;        // A row / B-C col
  const int g4   = lane >> 4;        // k-group / C row-group
  const int bset = blockIdx.x * 16;
  const int b0   = bset + 4 * g4;    // lane's first batch (C rows 4*g4..+3)

  // ---- W_hh fragments (prologue only); gates 0,1 pinned to AGPRs ----
  half8v wf[3][4][8];                // [gate][hidden-tile][kfrag]
  #pragma unroll
  for (int g = 0; g < 3; ++g)
    #pragma unroll
    for (int ht = 0; ht < 4; ++ht)
      #pragma unroll
      for (int kf = 0; kf < 8; ++kf) {
        const float* src = Whh + (size_t)(g * 256 + w * 64 + ht * 16 + c) * H_
                               + kf * 32 + g4 * 8;
        float4 u0 = *(const float4*)(src);
        float4 u1 = *(const float4*)(src + 4);
        half8v v;
        v[0] = (_Float16)u0.x; v[1] = (_Float16)u0.y;
        v[2] = (_Float16)u0.z; v[3] = (_Float16)u0.w;
        v[4] = (_Float16)u1.x; v[5] = (_Float16)u1.y;
        v[6] = (_Float16)u1.z; v[7] = (_Float16)u1.w;
        wf[g][ht][kf] = v;
        if (g < 2) asm volatile("" : "+a"(wf[g][ht][kf]));   // AGPR pin (r,z gates)
      }

  float bhn[4];
  #pragma unroll
  for (int ht = 0; ht < 4; ++ht) bhn[ht] = bhh[512 + w * 64 + ht * 16 + c];
  int len4[4];
  #pragma unroll
  for (int i = 0; i < 4; ++i) len4[i] = lengths[b0 + i];

  // h carry + LDS buffer 0 init
  float h[4][4];                     // [hidden-tile][batch-sub]
  #pragma unroll
  for (int ht = 0; ht < 4; ++ht)
    #pragma unroll
    for (int i = 0; i < 4; ++i) {
      float v = (t0 > 0) ? hws[(size_t)(b0 + i) * H_ + w * 64 + ht * 16 + c] : 0.f;
      h[ht][i] = v;
      int row = 4 * g4 + i;
      *(_Float16*)((char*)hlds + row * 528 +
                   (((w * 64 + ht * 16 + c) * 2) ^ ((row & 8) << 2))) = (_Float16)v;
    }
  __syncthreads();

  const f32x4 zero4 = {0.f, 0.f, 0.f, 0.f};
  int p = 0;
  for (int t = t0; t < t1; ++t) {
    // ---- A fragments from LDS (8 x ds_read_b128, XOR-swizzled) ----
    const char* hbase = (const char*)hlds + p * 8448 + c * 528;
    const int xr = (c & 8) << 2;
    half8v a[8];
    #pragma unroll
    for (int kf = 0; kf < 8; ++kf)
      a[kf] = *(const half8v*)(hbase + ((kf * 64 + g4 * 16) ^ xr));

    // ---- att (with length-mask folded) + pass-1 gi, issued before pass-1 MFMAs ----
    const float* gb0 = gi + ((size_t)(t - t0) * B_ + b0) * G3 + w * 64 + c;
    float wat[4];
    #pragma unroll
    for (int i = 0; i < 4; ++i) {
      float av = att[(size_t)(b0 + i) * T_ + t];
      wat[i] = (t < len4[i]) ? av : 0.f;   // wat==0 => h unchanged (mask semantics)
    }
    float gi1[3][2][4];
    #pragma unroll
    for (int i = 0; i < 4; ++i) {
      const float* gp = gb0 + (size_t)i * G3;
      #pragma unroll
      for (int g = 0; g < 3; ++g) {
        gi1[g][0][i] = gp[g * 256 +  0]; gi1[g][1][i] = gp[g * 256 + 16];
      }
    }

    char* wnext = (char*)hlds + (p ^ 1) * 8448;

    // ================= pass 1: hidden-tiles 0,1 =================
    f32x4 acc[3][2];
    #pragma unroll
    for (int g = 0; g < 3; ++g)
      #pragma unroll
      for (int h2 = 0; h2 < 2; ++h2)
        acc[g][h2] = MFMA16(a[0], wf[g][h2][0], zero4);
    #pragma unroll
    for (int kf = 1; kf < 8; ++kf)
      #pragma unroll
      for (int g = 0; g < 3; ++g)
        #pragma unroll
        for (int h2 = 0; h2 < 2; ++h2)
          acc[g][h2] = MFMA16(a[kf], wf[g][h2][kf], acc[g][h2]);

    // pass-2 gi issued here: covered by pass-1 epilogue + pass-2 MFMA chain
    float gi2[3][2][4];
    #pragma unroll
    for (int i = 0; i < 4; ++i) {
      const float* gp = gb0 + (size_t)i * G3;
      #pragma unroll
      for (int g = 0; g < 3; ++g) {
        gi2[g][0][i] = gp[g * 256 + 32]; gi2[g][1][i] = gp[g * 256 + 48];
      }
    }

    #pragma unroll
    for (int h2 = 0; h2 < 2; ++h2) {
      const int ht = h2;
      #pragma unroll
      for (int i = 0; i < 4; ++i) {
        float gr = gi1[0][h2][i] + acc[0][h2][i];
        float gz = gi1[1][h2][i] + acc[1][h2][i];
        float r  = 1.f / (1.f + __expf(-gr));
        float z  = 1.f / (1.f + __expf(-gz));
        float e2 = __expf(2.f * (gi1[2][h2][i] + r * (acc[2][h2][i] + bhn[ht])));
        float nn = 1.f - 2.f / (e2 + 1.f);
        float hold = h[ht][i];
        float hnew = (1.f - z) * nn + z * hold;
        float hv   = wat[i] * hnew + (1.f - wat[i]) * hold;
        h[ht][i] = hv;
        int row = 4 * g4 + i;
        *(_Float16*)(wnext + row * 528 +
                     (((w * 64 + ht * 16 + c) * 2) ^ ((row & 8) << 2))) = (_Float16)hv;
      }
    }

    // ================= pass 2: hidden-tiles 2,3 =================
    #pragma unroll
    for (int g = 0; g < 3; ++g)
      #pragma unroll
      for (int h2 = 0; h2 < 2; ++h2)
        acc[g][h2] = MFMA16(a[0], wf[g][2 + h2][0], zero4);
    #pragma unroll
    for (int kf = 1; kf < 8; ++kf)
      #pragma unroll
      for (int g = 0; g < 3; ++g)
        #pragma unroll
        for (int h2 = 0; h2 < 2; ++h2)
          acc[g][h2] = MFMA16(a[kf], wf[g][2 + h2][kf], acc[g][h2]);

    #pragma unroll
    for (int h2 = 0; h2 < 2; ++h2) {
      const int ht = 2 + h2;
      #pragma unroll
      for (int i = 0; i < 4; ++i) {
        float gr = gi2[0][h2][i] + acc[0][h2][i];
        float gz = gi2[1][h2][i] + acc[1][h2][i];
        float r  = 1.f / (1.f + __expf(-gr));
        float z  = 1.f / (1.f + __expf(-gz));
        float e2 = __expf(2.f * (gi2[2][h2][i] + r * (acc[2][h2][i] + bhn[ht])));
        float nn = 1.f - 2.f / (e2 + 1.f);
        float hold = h[ht][i];
        float hnew = (1.f - z) * nn + z * hold;
        float hv   = wat[i] * hnew + (1.f - wat[i]) * hold;
        h[ht][i] = hv;
        int row = 4 * g4 + i;
        *(_Float16*)(wnext + row * 528 +
                     (((w * 64 + ht * 16 + c) * 2) ^ ((row & 8) << 2))) = (_Float16)hv;
      }
    }

    __syncthreads();   // nothing in flight: all loads consumed this step
    p ^= 1;
  }

  #pragma unroll
  for (int ht = 0; ht < 4; ++ht)
    #pragma unroll
    for (int i = 0; i < 4; ++i) {
      size_t idx = (size_t)(b0 + i) * H_ + w * 64 + ht * 16 + c;
      hws[idx] = h[ht][i];
      if (t1 == T_) out[idx] = h[ht][i];
    }
}

extern "C" void kernel_launch(void* const* d_in, const int* in_sizes, int n_in,
                              void* d_out, int out_size, void* d_ws, size_t ws_size,
                              hipStream_t stream)
{
  const float* x       = (const float*)d_in[0];
  const float* att     = (const float*)d_in[1];
  const int*   lengths = (const int*)d_in[2];
  const float* Wih     = (const float*)d_in[3];
  const float* Whh     = (const float*)d_in[4];
  const float* bih     = (const float*)d_in[5];
  const float* bhh     = (const float*)d_in[6];
  float* out = (float*)d_out;

  float* hws = (float*)d_ws;                         // 64 KiB
  float* gi  = (float*)((char*)d_ws + 65536);
  const size_t used0 = 65536;
  const size_t per_t = (size_t)B_ * G3 * sizeof(float);
  size_t avail = ws_size > used0 ? ws_size - used0 : 0;
  int Tc = (int)(avail / per_t);
  if (Tc > T_) Tc = T_;
  if (Tc < 1) Tc = 1;

  for (int t0 = 0; t0 < T_; t0 += Tc) {
    int t1 = t0 + Tc; if (t1 > T_) t1 = T_;
    dim3 g1(t1 - t0, G3 / 64);
    gi_gemm<<<g1, 256, 0, stream>>>(x, Wih, bih, bhh, gi, t0);
    gru_mfma<<<4, 256, 0, stream>>>(gi, att, lengths, Whh, bhh, hws, out, t0, t1);
  }
}